// Round 7
// baseline (121.871 us; speedup 1.0000x reference)
//
#include <hip/hip_runtime.h>
#include <stdint.h>

#pragma clang fp contract(off)

typedef __attribute__((ext_vector_type(4))) int i32x4;
typedef __attribute__((ext_vector_type(16))) int i32x16;

#define B_    16
#define C_    128
#define HW_   56
#define L_    3136      // 56*56
#define CO_   128
#define F_    1152      // 128*9
#define M_    50176     // 16*3136

// ---- workspace layout (bytes) ----
#define OFF_SW   256        // float scale_w[128]
#define OFF_ZPW  768        // int   zp_w[128]
#define OFF_CT   1280       // int   const_term[128]
#define OFF_QW   4096       // int8  qw2[j][ch][o][16] = 9*8*128*16 = 147456
#define OFF_QX   153600     // int8  qx_t[b][l][c] = 6422528 (channel-last)
#define OFF_S    6576128    // int   S[b][3136] channel-sums = 200704
#define OFF_RES  6776832    // int   res[50176][128] = 25690112 (end ~32.5MB)

struct QP { unsigned xmin_enc, xmax_enc; int rmin, rmax; };

__device__ __forceinline__ unsigned enc_f(float f) {
    unsigned u = __float_as_uint(f);
    return (u & 0x80000000u) ? ~u : (u | 0x80000000u);
}
__device__ __forceinline__ float dec_f(unsigned e) {
    return __uint_as_float((e & 0x80000000u) ? (e ^ 0x80000000u) : ~e);
}
__device__ __forceinline__ int read_abit(const int* p) {
    int i = *p;
    if (i > 0 && i < 32) return i;
    float f = __int_as_float(i);
    int fi = (int)f;
    return (fi > 0 && fi < 32) ? fi : 8;
}
__device__ __forceinline__ void get_sx(const QP* P, int abit, float& sx, float& zx) {
    float xmin = dec_f(P->xmin_enc), xmax = dec_f(P->xmax_enc);
    float n = (float)((1 << abit) - 1);
    sx = n / fmaxf(xmax - xmin, 1e-8f);
    zx = rintf(sx * xmin) + (float)(1 << (abit - 1));
}

// ---------------- kernels ----------------

__global__ void k_init(char* ws) {
    if (threadIdx.x == 0) {
        QP* P = (QP*)ws;
        P->xmin_enc = 0x80000000u;  // enc(0.0f): padding zeros count
        P->xmax_enc = 0x80000000u;
        P->rmin = INT32_MAX;
        P->rmax = INT32_MIN;
    }
}

__global__ void k_xminmax(const float4* __restrict__ x4, int n4, char* ws) {
    QP* P = (QP*)ws;
    float mn = 0.0f, mx = 0.0f;
    int stride = gridDim.x * blockDim.x;
    for (int i = blockIdx.x * blockDim.x + threadIdx.x; i < n4; i += stride) {
        float4 v = x4[i];
        mn = fminf(mn, fminf(fminf(v.x, v.y), fminf(v.z, v.w)));
        mx = fmaxf(mx, fmaxf(fmaxf(v.x, v.y), fmaxf(v.z, v.w)));
    }
    for (int m = 32; m; m >>= 1) {
        mn = fminf(mn, __shfl_xor(mn, m));
        mx = fmaxf(mx, __shfl_xor(mx, m));
    }
    __shared__ float smn[4], smx[4];
    int w = threadIdx.x >> 6;
    if ((threadIdx.x & 63) == 0) { smn[w] = mn; smx[w] = mx; }
    __syncthreads();
    if (threadIdx.x == 0) {
        mn = fminf(fminf(smn[0], smn[1]), fminf(smn[2], smn[3]));
        mx = fmaxf(fmaxf(smx[0], smx[1]), fmaxf(smx[2], smx[3]));
        atomicMin(&P->xmin_enc, enc_f(mn));
        atomicMax(&P->xmax_enc, enc_f(mx));
    }
}

// one wave per output channel; packs qw2[j][ch][o][16]  (ch = c>>4, byte = c&15)
__global__ void k_wquant(const float* __restrict__ w, const float* __restrict__ bias,
                         const int* __restrict__ abit_p, char* ws) {
    QP* P = (QP*)ws;
    float* scale_w = (float*)(ws + OFF_SW);
    int* zpw = (int*)(ws + OFF_ZPW);
    int* ct  = (int*)(ws + OFF_CT);
    signed char* qw = (signed char*)(ws + OFF_QW);

    int o = blockIdx.x, lane = threadIdx.x;
    const float* wr = w + o * F_;
    float mn = 3.4e38f, mx = -3.4e38f;
    for (int f = lane; f < F_; f += 64) {
        float v = wr[f];
        mn = fminf(mn, v); mx = fmaxf(mx, v);
    }
    for (int m = 32; m; m >>= 1) {
        mn = fminf(mn, __shfl_xor(mn, m));
        mx = fmaxf(mx, __shfl_xor(mx, m));
    }
    float sw = 255.0f / fmaxf(mx - mn, 1e-8f);
    float zw = rintf(sw * mn) + 128.0f;

    int qsum = 0;
    for (int f = lane; f < F_; f += 64) {
        float q = fminf(fmaxf(rintf(sw * wr[f] - zw), -128.0f), 127.0f);
        int qi = (int)q;
        qsum += qi;
        int c = f / 9, j = f - c * 9;
        qw[j * 16384 + (c >> 4) * 2048 + (o << 4) + (c & 15)] = (signed char)qi;
    }
    for (int m = 32; m; m >>= 1) qsum += __shfl_xor(qsum, m);
    if (lane == 0) {
        int abit = read_abit(abit_p);
        float sx, zx; get_sx(P, abit, sx, zx);
        float qb = rintf(sw * sx * bias[o]);
        int zwi = (int)zw, zxi = (int)zx;
        ct[o] = zxi * qsum + F_ * zwi * zxi + (int)qb;
        zpw[o] = zwi;
        scale_w[o] = sw;
    }
}

// quantize to channel-last qx_t[b][l][c] + per-pixel channel sums S[b][l]
__global__ __launch_bounds__(256) void k_xquant(const float* __restrict__ x,
                                                const int* __restrict__ abit_p, char* ws) {
    __shared__ int ssum[4][64];
    QP* P = (QP*)ws;
    int abit = read_abit(abit_p);
    float sx, zx; get_sx(P, abit, sx, zx);
    int nx = 1 << (abit - 1);
    float lo = -(float)nx, hif = (float)(nx - 1);
    signed char* qxt = (signed char*)(ws + OFF_QX);
    int gid = blockIdx.x;
    int b = gid / 49, lcq = gid - b * 49;
    int l0 = lcq * 64;
    int t = threadIdx.x;
    int lane = t & 63, cg = t >> 6;
    int l = l0 + lane;
    const float* xb = x + ((size_t)b * C_) * L_ + l;
    int4* dst = (int4*)(qxt + ((size_t)(b * L_ + l)) * 128);
    int psum = 0;
    #pragma unroll
    for (int ii = 0; ii < 2; ++ii) {
        int c16 = (cg + 4 * ii) * 16;
        int wds[4];
        #pragma unroll
        for (int k = 0; k < 4; ++k) {
            int wv = 0;
            #pragma unroll
            for (int e = 0; e < 4; ++e) {
                int c = c16 + 4 * k + e;
                float v = xb[(size_t)c * L_];
                int qi = (int)fminf(fmaxf(rintf(sx * v - zx), lo), hif);
                psum += qi;
                wv |= (qi & 255) << (8 * e);
            }
            wds[k] = wv;
        }
        int4 vv; vv.x = wds[0]; vv.y = wds[1]; vv.z = wds[2]; vv.w = wds[3];
        dst[c16 >> 4] = vv;
    }
    ssum[cg][lane] = psum;
    __syncthreads();
    if (cg == 0) {
        int* S = (int*)(ws + OFF_S);
        S[b * L_ + l] = ssum[0][lane] + ssum[1][lane] + ssum[2][lane] + ssum[3][lane];
    }
}

// 64M x 128N MFMA int8 GEMM, single execution.
// 4 waves as 2Mx2N, each wave 32Mx64N (acc 2x i32x16).
// A: 4x58x128 halo staged once (XOR swizzle). B: per-tap 16KB LDS dbuf,
// reg-staged write-late/load-early, ONE barrier per tap.
// Epilogue: zero-point corrections, res write, global min/max atomics.
__global__ __launch_bounds__(256) void k_gemm(const int* __restrict__ abit_p,
                                              char* __restrict__ ws) {
    __shared__ __align__(16) signed char NB[4 * 58 * 128];   // 29696
    __shared__ __align__(16) signed char Bs[2][16384];
    __shared__ int S_s[232];
    __shared__ int sq_s[64];
    __shared__ int red[8];

    QP* P = (QP*)ws;
    const signed char* qxt = (const signed char*)(ws + OFF_QX);
    const signed char* qw  = (const signed char*)(ws + OFF_QW);
    const int* Sg    = (const int*)(ws + OFF_S);
    const int* zpw   = (const int*)(ws + OFF_ZPW);
    const int* ct    = (const int*)(ws + OFF_CT);
    int* res = (int*)(ws + OFF_RES);

    int t = threadIdx.x;
    int mg = blockIdx.x * 64;          // 784 blocks: 64-row tiles, no masking
    int b = mg / L_, l0 = mg - b * L_;
    int prow0 = l0 / HW_;              // tile spans pixel rows prow0, prow0+1

    int abit = read_abit(abit_p);
    float sx, zx; get_sx(P, abit, sx, zx);
    int nx = 1 << (abit - 1);
    int q0 = min(max(-(int)zx, -nx), nx - 1);
    int pw = (q0 & 255) * 0x01010101;
    int4 pad4; pad4.x = pw; pad4.y = pw; pad4.z = pw; pad4.w = pw;
    int padS = C_ * q0;

    const signed char* qxtb = qxt + (size_t)b * L_ * 128;
    const int* Sb = Sg + b * L_;

    // ---- prologue: load B tap0 to regs, write to Bs[0], load tap1 to regs ----
    int4 breg[4];
    {
        const int4* src = (const int4*)qw;
        #pragma unroll
        for (int k = 0; k < 4; ++k) breg[k] = src[k * 256 + t];
    }
    // stage A halo: 4 rows x 58 pix x 8 chunks = 1856 slots, swizzle ch ^= pix&7
    #pragma unroll
    for (int i = 0; i < 8; ++i) {
        int slot = t + i * 256;
        if (slot < 1856) {
            int pix = slot >> 3, ch = slot & 7;
            int ri = pix / 58, c1 = pix - ri * 58;
            int ih = prow0 - 1 + ri, iw = c1 - 1;
            int4 v = pad4;
            if ((unsigned)ih < HW_ && (unsigned)iw < HW_)
                v = *(const int4*)(qxtb + ((ih * HW_ + iw) << 7) + (ch << 4));
            *(int4*)&NB[(pix << 7) + ((ch ^ (pix & 7)) << 4)] = v;
        }
    }
    // stage S halo (232 entries)
    if (t < 232) {
        int ri = t / 58, c1 = t - ri * 58;
        int ih = prow0 - 1 + ri, iw = c1 - 1;
        S_s[t] = ((unsigned)ih < HW_ && (unsigned)iw < HW_) ? Sb[ih * HW_ + iw] : padS;
    }
    // write tap0 B to LDS, then issue tap1 loads
    {
        int4* d = (int4*)&Bs[0][0];
        #pragma unroll
        for (int k = 0; k < 4; ++k) d[k * 256 + t] = breg[k];
        const int4* src = (const int4*)(qw + 16384);
        #pragma unroll
        for (int k = 0; k < 4; ++k) breg[k] = src[k * 256 + t];
    }
    __syncthreads();

    // per-row 3x3 box sums from S_s
    if (t < 64) {
        int l = l0 + t;
        int oh = l / HW_, ow = l - oh * HW_;
        int ri = oh - prow0 + 1, ci = ow + 1;
        int s = 0;
        #pragma unroll
        for (int dr = -1; dr <= 1; ++dr)
            #pragma unroll
            for (int dc = -1; dc <= 1; ++dc)
                s += S_s[(ri + dr) * 58 + ci + dc];
        sq_s[t] = s;
    }

    int lane = t & 63, w = t >> 6;
    int wm = (w >> 1) << 5;            // 0 / 32
    int wn = (w & 1) << 6;             // 0 / 64
    int r = lane & 31, hi = lane >> 5;

    int l = l0 + wm + r;
    int oh = l / HW_, ow = l - oh * HW_;
    int pbase = (oh - prow0 + 1) * 58 + (ow + 1);

    i32x16 acc0, acc1;
    #pragma unroll
    for (int i = 0; i < 16; ++i) { acc0[i] = 0; acc1[i] = 0; }

    // ---- K-loop: 9 taps, ONE barrier per tap ----
    #pragma unroll
    for (int j = 0; j < 9; ++j) {
        if (j < 8) {
            // write tap j+1's B (loaded during tap j-1) into the idle buffer
            int4* d = (int4*)&Bs[(j + 1) & 1][0];
            #pragma unroll
            for (int k = 0; k < 4; ++k) d[k * 256 + t] = breg[k];
            if (j < 7) {
                const int4* src = (const int4*)(qw + (j + 2) * 16384);
                #pragma unroll
                for (int k = 0; k < 4; ++k) breg[k] = src[k * 256 + t];
            }
        }
        const signed char* Bcur = &Bs[j & 1][0];
        int pix = pbase + (j / 3 - 1) * 58 + (j % 3 - 1);
        i32x4 af[4], bf0[4], bf1[4];
        #pragma unroll
        for (int kk = 0; kk < 4; ++kk) {
            int ch2 = kk * 2 + hi;
            af[kk]  = *(const i32x4*)&NB[(pix << 7) + ((ch2 ^ (pix & 7)) << 4)];
            bf0[kk] = *(const i32x4*)&Bcur[ch2 * 2048 + ((wn + r) << 4)];
            bf1[kk] = *(const i32x4*)&Bcur[ch2 * 2048 + ((wn + 32 + r) << 4)];
        }
        #pragma unroll
        for (int kk = 0; kk < 4; ++kk) {
            acc0 = __builtin_amdgcn_mfma_i32_32x32x32_i8(af[kk], bf0[kk], acc0, 0, 0, 0);
            acc1 = __builtin_amdgcn_mfma_i32_32x32x32_i8(af[kk], bf1[kk], acc1, 0, 0, 0);
        }
        __syncthreads();
    }

    // ---- epilogue: corrections, res write, global min/max ----
    int o0 = wn + r, o1 = wn + 32 + r;
    int zw0 = zpw[o0], c0 = ct[o0];
    int zw1 = zpw[o1], c1 = ct[o1];
    int lmin = INT32_MAX, lmax = INT32_MIN;
    #pragma unroll
    for (int g = 0; g < 16; ++g) {
        int row = wm + (g & 3) + ((g >> 2) << 3) + (hi << 2);
        int m = mg + row;
        int s = sq_s[row];
        int v0 = acc0[g] + zw0 * s + c0;
        int v1 = acc1[g] + zw1 * s + c1;
        lmin = min(lmin, min(v0, v1));
        lmax = max(lmax, max(v0, v1));
        res[m * CO_ + o0] = v0;
        res[m * CO_ + o1] = v1;
    }
    for (int m = 32; m; m >>= 1) {
        lmin = min(lmin, __shfl_xor(lmin, m));
        lmax = max(lmax, __shfl_xor(lmax, m));
    }
    if ((t & 63) == 0) { red[t >> 6] = lmin; red[4 + (t >> 6)] = lmax; }
    __syncthreads();
    if (t == 0) {
        lmin = min(min(red[0], red[1]), min(red[2], red[3]));
        lmax = max(max(red[4], red[5]), max(red[6], red[7]));
        atomicMin(&P->rmin, lmin);
        atomicMax(&P->rmax, lmax);
    }
}

// requantize + dequantize with LDS tile transpose; out [B][Cout][L]
__global__ __launch_bounds__(256) void k_deq(const int* __restrict__ abit_p, char* ws,
                                             float* __restrict__ out) {
    __shared__ int tile[64 * 65];
    QP* P = (QP*)ws;
    const int* res = (const int*)(ws + OFF_RES);
    const float* scale_w = (const float*)(ws + OFF_SW);
    int t = threadIdx.x;
    int bid = blockIdx.x;
    int lcq = bid % 49; int tmp2 = bid / 49; int ocq = tmp2 & 1; int b = tmp2 >> 1;
    int l0 = lcq * 64, o0 = ocq * 64;

    const int* resb = res + ((size_t)(b * L_ + l0)) * CO_ + o0;
    #pragma unroll
    for (int i = 0; i < 4; ++i) {
        int lr = (t >> 4) + i * 16;
        int oc4 = (t & 15) * 4;
        int4 v = *(const int4*)(resb + lr * CO_ + oc4);
        int* d = &tile[lr * 65 + oc4];
        d[0] = v.x; d[1] = v.y; d[2] = v.z; d[3] = v.w;
    }

    int abit = read_abit(abit_p);
    float sxv, zxv; get_sx(P, abit, sxv, zxv);
    int nxq = 1 << (abit - 1);
    float nlev = (float)((1 << abit) - 1);
    float rmin = (float)P->rmin, rmax = (float)P->rmax;
    float sr = nlev / fmaxf(rmax - rmin, 1e-8f);
    float zr = rintf(sr * rmin) + (float)nxq;
    float lo = -(float)nxq, hiq = (float)(nxq - 1);

    __syncthreads();

    #pragma unroll
    for (int i = 0; i < 4; ++i) {
        int o = (t >> 4) + i * 16;
        int l4 = (t & 15) * 4;
        float swsx = scale_w[o0 + o] * sxv;
        float4 f;
        #pragma unroll
        for (int jj = 0; jj < 4; ++jj) {
            int rv = tile[(l4 + jj) * 65 + o];
            float q = fminf(fmaxf(rintf(sr * (float)rv - zr), lo), hiq);
            ((float*)&f)[jj] = ((q + zr) / sr) / swsx;
        }
        *(float4*)(out + ((size_t)(b * CO_ + o0 + o)) * L_ + l0 + l4) = f;
    }
}

// ---------------- launch ----------------

extern "C" void kernel_launch(void* const* d_in, const int* in_sizes, int n_in,
                              void* d_out, int out_size, void* d_ws, size_t ws_size,
                              hipStream_t stream) {
    const float* x      = (const float*)d_in[0];
    const float* weight = (const float*)d_in[1];
    const float* bias   = (const float*)d_in[2];
    const int*   abit   = (const int*)d_in[3];
    float* out = (float*)d_out;
    char* ws = (char*)d_ws;

    int n4 = (B_ * C_ * L_) / 4;

    k_init<<<1, 64, 0, stream>>>(ws);
    k_xminmax<<<1024, 256, 0, stream>>>((const float4*)x, n4, ws);
    k_wquant<<<128, 64, 0, stream>>>(weight, bias, abit, ws);
    k_xquant<<<784, 256, 0, stream>>>(x, abit, ws);
    k_gemm<<<M_ / 64, 256, 0, stream>>>(abit, ws);
    k_deq<<<1568, 256, 0, stream>>>(abit, ws, out);
}

// Round 8
// 113.891 us; speedup vs baseline: 1.0701x; 1.0701x over previous
//
#include <hip/hip_runtime.h>
#include <stdint.h>

#pragma clang fp contract(off)

typedef __attribute__((ext_vector_type(4))) int i32x4;
typedef __attribute__((ext_vector_type(16))) int i32x16;

#define B_    16
#define C_    128
#define HW_   56
#define L_    3136      // 56*56
#define CO_   128
#define F_    1152      // 128*9
#define M_    50176     // 16*3136

// ---- workspace layout (bytes) ----
#define OFF_SW   256        // float scale_w[128]
#define OFF_ZPW  768        // int   zp_w[128]
#define OFF_CT   1280       // int   const_term[128]
#define OFF_QW   4096       // int8  qw2[j][ch][o][16] = 9*8*128*16 = 147456
#define OFF_QX   153600     // int8  qx_t[b][l][c] = 6422528 (channel-last)
#define OFF_S    6576128    // int   S[b][3136] channel-sums = 200704
#define OFF_RES  6776832    // int   res[50176][128] = 25690112 (end ~32.5MB)

struct QP { unsigned xmin_enc, xmax_enc; int rmin, rmax; };

__device__ __forceinline__ unsigned enc_f(float f) {
    unsigned u = __float_as_uint(f);
    return (u & 0x80000000u) ? ~u : (u | 0x80000000u);
}
__device__ __forceinline__ float dec_f(unsigned e) {
    return __uint_as_float((e & 0x80000000u) ? (e ^ 0x80000000u) : ~e);
}
__device__ __forceinline__ int read_abit(const int* p) {
    int i = *p;
    if (i > 0 && i < 32) return i;
    float f = __int_as_float(i);
    int fi = (int)f;
    return (fi > 0 && fi < 32) ? fi : 8;
}
__device__ __forceinline__ void get_sx(const QP* P, int abit, float& sx, float& zx) {
    float xmin = dec_f(P->xmin_enc), xmax = dec_f(P->xmax_enc);
    float n = (float)((1 << abit) - 1);
    sx = n / fmaxf(xmax - xmin, 1e-8f);
    zx = rintf(sx * xmin) + (float)(1 << (abit - 1));
}

// ---------------- kernels ----------------

__global__ void k_init(char* ws) {
    if (threadIdx.x == 0) {
        QP* P = (QP*)ws;
        P->xmin_enc = 0x80000000u;  // enc(0.0f): padding zeros count
        P->xmax_enc = 0x80000000u;
        P->rmin = INT32_MAX;
        P->rmax = INT32_MIN;
    }
}

__global__ void k_xminmax(const float4* __restrict__ x4, int n4, char* ws) {
    QP* P = (QP*)ws;
    float mn = 0.0f, mx = 0.0f;
    int stride = gridDim.x * blockDim.x;
    for (int i = blockIdx.x * blockDim.x + threadIdx.x; i < n4; i += stride) {
        float4 v = x4[i];
        mn = fminf(mn, fminf(fminf(v.x, v.y), fminf(v.z, v.w)));
        mx = fmaxf(mx, fmaxf(fmaxf(v.x, v.y), fmaxf(v.z, v.w)));
    }
    for (int m = 32; m; m >>= 1) {
        mn = fminf(mn, __shfl_xor(mn, m));
        mx = fmaxf(mx, __shfl_xor(mx, m));
    }
    __shared__ float smn[4], smx[4];
    int w = threadIdx.x >> 6;
    if ((threadIdx.x & 63) == 0) { smn[w] = mn; smx[w] = mx; }
    __syncthreads();
    if (threadIdx.x == 0) {
        mn = fminf(fminf(smn[0], smn[1]), fminf(smn[2], smn[3]));
        mx = fmaxf(fmaxf(smx[0], smx[1]), fmaxf(smx[2], smx[3]));
        atomicMin(&P->xmin_enc, enc_f(mn));
        atomicMax(&P->xmax_enc, enc_f(mx));
    }
}

// merged: blocks 0..783 quantize x (channel-last) + channel sums;
//         blocks 784..911 quantize weights (wave 0 only), pack qw2[j][ch][o][16]
__global__ __launch_bounds__(256) void k_wxq(const float* __restrict__ x,
                                             const float* __restrict__ w,
                                             const float* __restrict__ bias,
                                             const int* __restrict__ abit_p, char* ws) {
    QP* P = (QP*)ws;
    int abit = read_abit(abit_p);
    float sx, zx; get_sx(P, abit, sx, zx);
    int gid = blockIdx.x;
    int t = threadIdx.x;

    if (gid >= 784) {                          // ---- weight quant ----
        if (t >= 64) return;
        int o = gid - 784, lane = t;
        float* scale_w = (float*)(ws + OFF_SW);
        int* zpw = (int*)(ws + OFF_ZPW);
        int* ct  = (int*)(ws + OFF_CT);
        signed char* qw = (signed char*)(ws + OFF_QW);
        const float* wr = w + o * F_;
        float mn = 3.4e38f, mx = -3.4e38f;
        for (int f = lane; f < F_; f += 64) {
            float v = wr[f];
            mn = fminf(mn, v); mx = fmaxf(mx, v);
        }
        for (int m = 32; m; m >>= 1) {
            mn = fminf(mn, __shfl_xor(mn, m));
            mx = fmaxf(mx, __shfl_xor(mx, m));
        }
        float sw = 255.0f / fmaxf(mx - mn, 1e-8f);
        float zw = rintf(sw * mn) + 128.0f;
        int qsum = 0;
        for (int f = lane; f < F_; f += 64) {
            float q = fminf(fmaxf(rintf(sw * wr[f] - zw), -128.0f), 127.0f);
            int qi = (int)q;
            qsum += qi;
            int c = f / 9, j = f - c * 9;
            qw[j * 16384 + (c >> 4) * 2048 + (o << 4) + (c & 15)] = (signed char)qi;
        }
        for (int m = 32; m; m >>= 1) qsum += __shfl_xor(qsum, m);
        if (lane == 0) {
            float qb = rintf(sw * sx * bias[o]);
            int zwi = (int)zw, zxi = (int)zx;
            ct[o] = zxi * qsum + F_ * zwi * zxi + (int)qb;
            zpw[o] = zwi;
            scale_w[o] = sw;
        }
        return;
    }

    // ---- x quant ----
    __shared__ int ssum[4][64];
    int nx = 1 << (abit - 1);
    float lo = -(float)nx, hif = (float)(nx - 1);
    signed char* qxt = (signed char*)(ws + OFF_QX);
    int b = gid / 49, lcq = gid - b * 49;
    int l0 = lcq * 64;
    int lane = t & 63, cg = t >> 6;
    int l = l0 + lane;
    const float* xb = x + ((size_t)b * C_) * L_ + l;
    int4* dst = (int4*)(qxt + ((size_t)(b * L_ + l)) * 128);
    int psum = 0;
    #pragma unroll
    for (int ii = 0; ii < 2; ++ii) {
        int c16 = (cg + 4 * ii) * 16;
        int wds[4];
        #pragma unroll
        for (int k = 0; k < 4; ++k) {
            int wv = 0;
            #pragma unroll
            for (int e = 0; e < 4; ++e) {
                int c = c16 + 4 * k + e;
                float v = xb[(size_t)c * L_];
                int qi = (int)fminf(fmaxf(rintf(sx * v - zx), lo), hif);
                psum += qi;
                wv |= (qi & 255) << (8 * e);
            }
            wds[k] = wv;
        }
        int4 vv; vv.x = wds[0]; vv.y = wds[1]; vv.z = wds[2]; vv.w = wds[3];
        dst[c16 >> 4] = vv;
    }
    ssum[cg][lane] = psum;
    __syncthreads();
    if (cg == 0) {
        int* S = (int*)(ws + OFF_S);
        S[b * L_ + l] = ssum[0][lane] + ssum[1][lane] + ssum[2][lane] + ssum[3][lane];
    }
}

// 64M x 128N MFMA int8 GEMM. High-occupancy R2 shape (~25.8KB LDS, 4 blocks/CU):
// single-buffered As (8KB, XOR swizzle) + Bs (16KB linear), 2 barriers/tap,
// A+B global loads for tap j+1 issued in registers during tap j's compute.
__global__ __launch_bounds__(256) void k_gemm(const int* __restrict__ abit_p,
                                              char* __restrict__ ws) {
    __shared__ __align__(16) signed char As[8192];     // [64 rows][8 chunks swz][16]
    __shared__ __align__(16) signed char Bs[16384];    // [8 ch][128 o][16] linear
    __shared__ int S_s[232];
    __shared__ int sq_s[64];
    __shared__ int red[8];

    QP* P = (QP*)ws;
    const signed char* qxt = (const signed char*)(ws + OFF_QX);
    const signed char* qw  = (const signed char*)(ws + OFF_QW);
    const int* Sg    = (const int*)(ws + OFF_S);
    const int* zpw   = (const int*)(ws + OFF_ZPW);
    const int* ct    = (const int*)(ws + OFF_CT);
    int* res = (int*)(ws + OFF_RES);

    int t = threadIdx.x;
    int mg = blockIdx.x * 64;          // 64-row tiles never cross batch (64|3136)
    int b = mg / L_, l0 = mg - b * L_;
    int prow0 = l0 / HW_;

    int abit = read_abit(abit_p);
    float sx, zx; get_sx(P, abit, sx, zx);
    int nx = 1 << (abit - 1);
    int q0 = min(max(-(int)zx, -nx), nx - 1);
    int pw = (q0 & 255) * 0x01010101;
    int4 pad4; pad4.x = pw; pad4.y = pw; pad4.z = pw; pad4.w = pw;
    int padS = C_ * q0;

    const signed char* qxtb = qxt + (size_t)b * L_ * 128;
    const int* Sb = Sg + b * L_;

    // per-thread A staging identity: rows t>>3 and +32, chunk t&7
    int chA = t & 7;
    int rowA0 = t >> 3, rowA1 = rowA0 + 32;
    int li0 = l0 + rowA0, li1 = l0 + rowA1;
    int oh0 = li0 / HW_, ow0 = li0 - oh0 * HW_;
    int oh1 = li1 / HW_, ow1 = li1 - oh1 * HW_;

    int4 a0, a1, br[4];
    #define LOAD_A(J) do {                                                        \
        int kh = (J) / 3 - 1, kw = (J) % 3 - 1;                                   \
        int ih = oh0 + kh, iw = ow0 + kw;                                         \
        a0 = ((unsigned)ih < HW_ && (unsigned)iw < HW_)                           \
             ? *(const int4*)(qxtb + ((ih * HW_ + iw) << 7) + (chA << 4)) : pad4; \
        ih = oh1 + kh; iw = ow1 + kw;                                             \
        a1 = ((unsigned)ih < HW_ && (unsigned)iw < HW_)                           \
             ? *(const int4*)(qxtb + ((ih * HW_ + iw) << 7) + (chA << 4)) : pad4; \
    } while (0)
    #define LOAD_B(J) do {                                                        \
        const int4* src = (const int4*)(qw + (J) * 16384);                        \
        br[0] = src[t]; br[1] = src[256 + t];                                     \
        br[2] = src[512 + t]; br[3] = src[768 + t];                               \
    } while (0)
    #define WRITE_AB() do {                                                       \
        *(int4*)&As[(rowA0 << 7) + ((chA ^ (rowA0 & 7)) << 4)] = a0;              \
        *(int4*)&As[(rowA1 << 7) + ((chA ^ (rowA1 & 7)) << 4)] = a1;              \
        int4* d = (int4*)Bs;                                                      \
        d[t] = br[0]; d[256 + t] = br[1]; d[512 + t] = br[2]; d[768 + t] = br[3]; \
    } while (0)

    // ---- prologue ----
    LOAD_A(0); LOAD_B(0);
    if (t < 232) {                      // S halo
        int ri = t / 58, c1 = t - ri * 58;
        int ih = prow0 - 1 + ri, iw = c1 - 1;
        S_s[t] = ((unsigned)ih < HW_ && (unsigned)iw < HW_) ? Sb[ih * HW_ + iw] : padS;
    }
    WRITE_AB();
    LOAD_A(1); LOAD_B(1);
    __syncthreads();
    if (t < 64) {                       // per-row 3x3 box sums
        int l = l0 + t;
        int oh = l / HW_, ow = l - oh * HW_;
        int ri = oh - prow0 + 1, ci = ow + 1;
        int s = 0;
        #pragma unroll
        for (int dr = -1; dr <= 1; ++dr)
            #pragma unroll
            for (int dc = -1; dc <= 1; ++dc)
                s += S_s[(ri + dr) * 58 + ci + dc];
        sq_s[t] = s;
    }

    int lane = t & 63, w = t >> 6;
    int wm = (w >> 1) << 5;            // 0 / 32
    int wn = (w & 1) << 6;             // 0 / 64
    int r = lane & 31, hi = lane >> 5;

    i32x16 acc0, acc1;
    #pragma unroll
    for (int i = 0; i < 16; ++i) { acc0[i] = 0; acc1[i] = 0; }

    // ---- K-loop: 9 taps ----
    #pragma unroll
    for (int j = 0; j < 9; ++j) {
        i32x4 af[4], bf0[4], bf1[4];
        #pragma unroll
        for (int kk = 0; kk < 4; ++kk) {
            int ch2 = kk * 2 + hi;
            int row = wm + r;
            af[kk]  = *(const i32x4*)&As[(row << 7) + ((ch2 ^ (row & 7)) << 4)];
            bf0[kk] = *(const i32x4*)&Bs[ch2 * 2048 + ((wn + r) << 4)];
            bf1[kk] = *(const i32x4*)&Bs[ch2 * 2048 + ((wn + 32 + r) << 4)];
        }
        #pragma unroll
        for (int kk = 0; kk < 4; ++kk) {
            acc0 = __builtin_amdgcn_mfma_i32_32x32x32_i8(af[kk], bf0[kk], acc0, 0, 0, 0);
            acc1 = __builtin_amdgcn_mfma_i32_32x32x32_i8(af[kk], bf1[kk], acc1, 0, 0, 0);
        }
        if (j < 8) {
            __syncthreads();           // tap j reads done (WAR)
            WRITE_AB();                // tap j+1 from regs
            if (j < 7) { LOAD_A(j + 2); LOAD_B(j + 2); }
            __syncthreads();           // tap j+1 visible (RAW)
        }
    }

    // ---- epilogue: corrections, res write, global min/max ----
    int o0 = wn + r, o1 = wn + 32 + r;
    int zw0 = zpw[o0], c0 = ct[o0];
    int zw1 = zpw[o1], c1 = ct[o1];
    int lmin = INT32_MAX, lmax = INT32_MIN;
    #pragma unroll
    for (int g = 0; g < 16; ++g) {
        int row = wm + (g & 3) + ((g >> 2) << 3) + (hi << 2);
        int m = mg + row;
        int s = sq_s[row];
        int v0 = acc0[g] + zw0 * s + c0;
        int v1 = acc1[g] + zw1 * s + c1;
        lmin = min(lmin, min(v0, v1));
        lmax = max(lmax, max(v0, v1));
        res[m * CO_ + o0] = v0;
        res[m * CO_ + o1] = v1;
    }
    for (int m = 32; m; m >>= 1) {
        lmin = min(lmin, __shfl_xor(lmin, m));
        lmax = max(lmax, __shfl_xor(lmax, m));
    }
    if ((t & 63) == 0) { red[t >> 6] = lmin; red[4 + (t >> 6)] = lmax; }
    __syncthreads();
    if (t == 0) {
        lmin = min(min(red[0], red[1]), min(red[2], red[3]));
        lmax = max(max(red[4], red[5]), max(red[6], red[7]));
        atomicMin(&P->rmin, lmin);
        atomicMax(&P->rmax, lmax);
    }
    #undef LOAD_A
    #undef LOAD_B
    #undef WRITE_AB
}

// requantize + dequantize with LDS tile transpose; out [B][Cout][L]
__global__ __launch_bounds__(256) void k_deq(const int* __restrict__ abit_p, char* ws,
                                             float* __restrict__ out) {
    __shared__ int tile[64 * 65];
    QP* P = (QP*)ws;
    const int* res = (const int*)(ws + OFF_RES);
    const float* scale_w = (const float*)(ws + OFF_SW);
    int t = threadIdx.x;
    int bid = blockIdx.x;
    int lcq = bid % 49; int tmp2 = bid / 49; int ocq = tmp2 & 1; int b = tmp2 >> 1;
    int l0 = lcq * 64, o0 = ocq * 64;

    const int* resb = res + ((size_t)(b * L_ + l0)) * CO_ + o0;
    #pragma unroll
    for (int i = 0; i < 4; ++i) {
        int lr = (t >> 4) + i * 16;
        int oc4 = (t & 15) * 4;
        int4 v = *(const int4*)(resb + lr * CO_ + oc4);
        int* d = &tile[lr * 65 + oc4];
        d[0] = v.x; d[1] = v.y; d[2] = v.z; d[3] = v.w;
    }

    int abit = read_abit(abit_p);
    float sxv, zxv; get_sx(P, abit, sxv, zxv);
    int nxq = 1 << (abit - 1);
    float nlev = (float)((1 << abit) - 1);
    float rmin = (float)P->rmin, rmax = (float)P->rmax;
    float sr = nlev / fmaxf(rmax - rmin, 1e-8f);
    float zr = rintf(sr * rmin) + (float)nxq;
    float lo = -(float)nxq, hiq = (float)(nxq - 1);

    __syncthreads();

    #pragma unroll
    for (int i = 0; i < 4; ++i) {
        int o = (t >> 4) + i * 16;
        int l4 = (t & 15) * 4;
        float swsx = scale_w[o0 + o] * sxv;
        float4 f;
        #pragma unroll
        for (int jj = 0; jj < 4; ++jj) {
            int rv = tile[(l4 + jj) * 65 + o];
            float q = fminf(fmaxf(rintf(sr * (float)rv - zr), lo), hiq);
            ((float*)&f)[jj] = ((q + zr) / sr) / swsx;
        }
        *(float4*)(out + ((size_t)(b * CO_ + o0 + o)) * L_ + l0 + l4) = f;
    }
}

// ---------------- launch ----------------

extern "C" void kernel_launch(void* const* d_in, const int* in_sizes, int n_in,
                              void* d_out, int out_size, void* d_ws, size_t ws_size,
                              hipStream_t stream) {
    const float* x      = (const float*)d_in[0];
    const float* weight = (const float*)d_in[1];
    const float* bias   = (const float*)d_in[2];
    const int*   abit   = (const int*)d_in[3];
    float* out = (float*)d_out;
    char* ws = (char*)d_ws;

    int n4 = (B_ * C_ * L_) / 4;

    k_init<<<1, 64, 0, stream>>>(ws);
    k_xminmax<<<1024, 256, 0, stream>>>((const float4*)x, n4, ws);
    k_wxq<<<912, 256, 0, stream>>>(x, weight, bias, abit, ws);
    k_gemm<<<M_ / 64, 256, 0, stream>>>(abit, ws);
    k_deq<<<1568, 256, 0, stream>>>(abit, ws, out);
}

// Round 9
// 59.417 us; speedup vs baseline: 2.0511x; 1.9168x over previous
//
#include <hip/hip_runtime.h>
#include <hip/hip_cooperative_groups.h>
#include <stdint.h>

#pragma clang fp contract(off)

namespace cg = cooperative_groups;

typedef __attribute__((ext_vector_type(4))) int i32x4;
typedef __attribute__((ext_vector_type(16))) int i32x16;

#define B_    16
#define C_    128
#define HW_   56
#define L_    3136
#define CO_   128
#define F_    1152
#define M_    50176
#define NT_   784          // GEMM tiles == grid blocks

// ---- workspace layout (bytes) ----
#define OFF_PBMIN 0        // float[784] per-block x-min partials
#define OFF_PBMAX 3136     // float[784]
#define OFF_PRMIN 6272     // int[784] per-block res-min partials
#define OFF_PRMAX 9408     // int[784]
#define OFF_SW    12544    // float scale_w[128]
#define OFF_ZPW   13056    // int zp_w[128]
#define OFF_CT    13568    // int const_term[128]
#define OFF_QW    16384    // int8 qw2[j][ch][o][16] = 147456
#define OFF_QX    163840   // int8 qx_t[b][l][c] = 6422528
#define OFF_S     6586368  // int S[b][3136] = 200704
#define OFF_RES   6787072  // int res[50176][128] (FALLBACK PATH ONLY)

__device__ __forceinline__ int read_abit(const int* p) {
    int i = *p;
    if (i > 0 && i < 32) return i;
    float f = __int_as_float(i);
    int fi = (int)f;
    return (fi > 0 && fi < 32) ? fi : 8;
}

// ---- block-wide reductions (256 threads), trailing sync for LDS reuse ----
__device__ __forceinline__ void block_fminmax(float& mn, float& mx, float* sred) {
    for (int m = 32; m; m >>= 1) {
        mn = fminf(mn, __shfl_xor(mn, m));
        mx = fmaxf(mx, __shfl_xor(mx, m));
    }
    int w = threadIdx.x >> 6;
    if ((threadIdx.x & 63) == 0) { sred[w] = mn; sred[4 + w] = mx; }
    __syncthreads();
    mn = fminf(fminf(sred[0], sred[1]), fminf(sred[2], sred[3]));
    mx = fmaxf(fmaxf(sred[4], sred[5]), fmaxf(sred[6], sred[7]));
    __syncthreads();
}
__device__ __forceinline__ void block_iminmax(int& mn, int& mx, int* ired) {
    for (int m = 32; m; m >>= 1) {
        mn = min(mn, __shfl_xor(mn, m));
        mx = max(mx, __shfl_xor(mx, m));
    }
    int w = threadIdx.x >> 6;
    if ((threadIdx.x & 63) == 0) { ired[w] = mn; ired[4 + w] = mx; }
    __syncthreads();
    mn = min(min(ired[0], ired[1]), min(ired[2], ired[3]));
    mx = max(max(ired[4], ired[5]), max(ired[6], ired[7]));
    __syncthreads();
}
__device__ __forceinline__ int block_isum(int v, int* ired) {
    for (int m = 32; m; m >>= 1) v += __shfl_xor(v, m);
    int w = threadIdx.x >> 6;
    if ((threadIdx.x & 63) == 0) ired[w] = v;
    __syncthreads();
    v = ired[0] + ired[1] + ired[2] + ired[3];
    __syncthreads();
    return v;
}

// ---- P1: per-block x min/max partials (pad zeros included via 0-init) ----
__device__ __forceinline__ void dev_p1(const float4* __restrict__ x4, int n4,
                                       char* ws, float* sred) {
    float mn = 0.0f, mx = 0.0f;
    int stride = gridDim.x * blockDim.x;
    for (int i = blockIdx.x * blockDim.x + threadIdx.x; i < n4; i += stride) {
        float4 v = x4[i];
        mn = fminf(mn, fminf(fminf(v.x, v.y), fminf(v.z, v.w)));
        mx = fmaxf(mx, fmaxf(fmaxf(v.x, v.y), fmaxf(v.z, v.w)));
    }
    block_fminmax(mn, mx, sred);
    if (threadIdx.x == 0) {
        ((float*)(ws + OFF_PBMIN))[blockIdx.x] = mn;
        ((float*)(ws + OFF_PBMAX))[blockIdx.x] = mx;
    }
}

__device__ __forceinline__ void dev_reduce_pb(const char* ws, float* sred,
                                              float& xmin, float& xmax) {
    const float* pbmin = (const float*)(ws + OFF_PBMIN);
    const float* pbmax = (const float*)(ws + OFF_PBMAX);
    float mn = 0.0f, mx = 0.0f;
    for (int i = threadIdx.x; i < NT_; i += 256) {
        mn = fminf(mn, pbmin[i]);
        mx = fmaxf(mx, pbmax[i]);
    }
    block_fminmax(mn, mx, sred);
    xmin = mn; xmax = mx;
}

__device__ __forceinline__ void dev_reduce_pr(const char* ws, int* ired,
                                              int& rmin, int& rmax) {
    const int* prmin = (const int*)(ws + OFF_PRMIN);
    const int* prmax = (const int*)(ws + OFF_PRMAX);
    int mn = INT32_MAX, mx = INT32_MIN;
    for (int i = threadIdx.x; i < NT_; i += 256) {
        mn = min(mn, prmin[i]);
        mx = max(mx, prmax[i]);
    }
    block_iminmax(mn, mx, ired);
    rmin = mn; rmax = mx;
}

// ---- P2x: quantize x to channel-last qx_t + per-pixel channel sums S ----
__device__ __forceinline__ void dev_p2x(const float* __restrict__ x, char* ws, char* pool,
                                        float sx, float zx, int nx) {
    int (*ssum)[64] = (int(*)[64])pool;
    float lo = -(float)nx, hif = (float)(nx - 1);
    signed char* qxt = (signed char*)(ws + OFF_QX);
    int gid = blockIdx.x;
    int b = gid / 49, lcq = gid - b * 49;
    int l0 = lcq * 64;
    int t = threadIdx.x, lane = t & 63, cgp = t >> 6;
    int l = l0 + lane;
    const float* xb = x + ((size_t)b * C_) * L_ + l;
    int4* dst = (int4*)(qxt + ((size_t)(b * L_ + l)) * 128);
    int psum = 0;
    #pragma unroll
    for (int ii = 0; ii < 2; ++ii) {
        int c16 = (cgp + 4 * ii) * 16;
        int wds[4];
        #pragma unroll
        for (int k = 0; k < 4; ++k) {
            int wv = 0;
            #pragma unroll
            for (int e = 0; e < 4; ++e) {
                int c = c16 + 4 * k + e;
                float v = xb[(size_t)c * L_];
                int qi = (int)fminf(fmaxf(rintf(sx * v - zx), lo), hif);
                psum += qi;
                wv |= (qi & 255) << (8 * e);
            }
            wds[k] = wv;
        }
        int4 vv; vv.x = wds[0]; vv.y = wds[1]; vv.z = wds[2]; vv.w = wds[3];
        dst[c16 >> 4] = vv;
    }
    ssum[cgp][lane] = psum;
    __syncthreads();
    if (cgp == 0) {
        int* S = (int*)(ws + OFF_S);
        S[b * L_ + l] = ssum[0][lane] + ssum[1][lane] + ssum[2][lane] + ssum[3][lane];
    }
    __syncthreads();
}

// ---- P2w: quantize weight row o=blockIdx.x (256 threads), pack qw2[j][ch][o][16] ----
__device__ __forceinline__ void dev_p2w(const float* __restrict__ wgt,
                                        const float* __restrict__ bias,
                                        char* ws, float* sred, int* ired,
                                        float sx, float zx) {
    int o = blockIdx.x;
    const float* wr = wgt + o * F_;
    float mn = 3.4e38f, mx = -3.4e38f;
    for (int f = threadIdx.x; f < F_; f += 256) {
        float v = wr[f];
        mn = fminf(mn, v); mx = fmaxf(mx, v);
    }
    block_fminmax(mn, mx, sred);
    float sw = 255.0f / fmaxf(mx - mn, 1e-8f);
    float zw = rintf(sw * mn) + 128.0f;
    signed char* qw = (signed char*)(ws + OFF_QW);
    int qsum = 0;
    for (int f = threadIdx.x; f < F_; f += 256) {
        float q = fminf(fmaxf(rintf(sw * wr[f] - zw), -128.0f), 127.0f);
        int qi = (int)q;
        qsum += qi;
        int c = f / 9, j = f - c * 9;
        qw[j * 16384 + (c >> 4) * 2048 + (o << 4) + (c & 15)] = (signed char)qi;
    }
    qsum = block_isum(qsum, ired);
    if (threadIdx.x == 0) {
        float qb = rintf(sw * sx * bias[o]);
        int zwi = (int)zw, zxi = (int)zx;
        ((int*)(ws + OFF_CT))[o] = zxi * qsum + F_ * zwi * zxi + (int)qb;
        ((int*)(ws + OFF_ZPW))[o] = zwi;
        ((float*)(ws + OFF_SW))[o] = sw;
    }
}

// ---- P3: 64Mx128N MFMA int8 GEMM tile; corrected accs stay in registers ----
// pool layout: As 0..8191 | Bs 8192..24575 | S_s 24576..25503 | sq 25504..25759
template <bool WRITE_RES>
__device__ __forceinline__ void dev_p3(char* __restrict__ ws, char* pool, int* ired,
                                       int abit, float sx, float zx,
                                       i32x16& acc0, i32x16& acc1) {
    signed char* As = (signed char*)pool;
    signed char* Bs = (signed char*)(pool + 8192);
    int* S_s = (int*)(pool + 24576);
    int* sq  = (int*)(pool + 25504);
    const signed char* qxt = (const signed char*)(ws + OFF_QX);
    const signed char* qw  = (const signed char*)(ws + OFF_QW);
    const int* Sg  = (const int*)(ws + OFF_S);
    const int* zpw = (const int*)(ws + OFF_ZPW);
    const int* ct  = (const int*)(ws + OFF_CT);

    int t = threadIdx.x;
    int mg = blockIdx.x * 64;
    int b = mg / L_, l0 = mg - b * L_;
    int prow0 = l0 / HW_;
    int nx = 1 << (abit - 1);
    int q0 = min(max(-(int)zx, -nx), nx - 1);
    int pw = (q0 & 255) * 0x01010101;
    int4 pad4; pad4.x = pw; pad4.y = pw; pad4.z = pw; pad4.w = pw;
    int padS = C_ * q0;
    const signed char* qxtb = qxt + (size_t)b * L_ * 128;
    const int* Sb = Sg + b * L_;

    int chA = t & 7, rowA0 = t >> 3, rowA1 = rowA0 + 32;
    int li0 = l0 + rowA0, li1 = l0 + rowA1;
    int oh0 = li0 / HW_, ow0 = li0 - oh0 * HW_;
    int oh1 = li1 / HW_, ow1 = li1 - oh1 * HW_;

    // B tap0 prefetch + S halo
    int4 br0, br1, br2, br3;
    {
        const int4* src = (const int4*)qw;
        br0 = src[t]; br1 = src[256 + t]; br2 = src[512 + t]; br3 = src[768 + t];
    }
    if (t < 232) {
        int ri = t / 58, c1 = t - ri * 58;
        int ih = prow0 - 1 + ri, iw = c1 - 1;
        S_s[t] = ((unsigned)ih < HW_ && (unsigned)iw < HW_) ? Sb[ih * HW_ + iw] : padS;
    }
    __syncthreads();
    if (t < 64) {               // per-row 3x3 box sums
        int l = l0 + t;
        int oh = l / HW_, ow = l - oh * HW_;
        int ri = oh - prow0 + 1, ci = ow + 1;
        int s = 0;
        #pragma unroll
        for (int dr = -1; dr <= 1; ++dr)
            #pragma unroll
            for (int dc = -1; dc <= 1; ++dc)
                s += S_s[(ri + dr) * 58 + ci + dc];
        sq[t] = s;
    }

    int lane = t & 63, w = t >> 6;
    int wm = (w >> 1) << 5, wn = (w & 1) << 6;
    int r = lane & 31, hi = lane >> 5;
    #pragma unroll
    for (int i = 0; i < 16; ++i) { acc0[i] = 0; acc1[i] = 0; }

    #pragma unroll
    for (int j = 0; j < 9; ++j) {
        if (j > 0) __syncthreads();            // WAR: previous tap's reads done
        {
            int kh = j / 3 - 1, kw = j % 3 - 1;
            int ih = oh0 + kh, iw = ow0 + kw;
            int4 a0 = ((unsigned)ih < HW_ && (unsigned)iw < HW_)
                      ? *(const int4*)(qxtb + ((ih * HW_ + iw) << 7) + (chA << 4)) : pad4;
            int ih1 = oh1 + kh, iw1 = ow1 + kw;
            int4 a1 = ((unsigned)ih1 < HW_ && (unsigned)iw1 < HW_)
                      ? *(const int4*)(qxtb + ((ih1 * HW_ + iw1) << 7) + (chA << 4)) : pad4;
            int4* d = (int4*)Bs;
            d[t] = br0; d[256 + t] = br1; d[512 + t] = br2; d[768 + t] = br3;
            if (j < 8) {
                const int4* src = (const int4*)(qw + (j + 1) * 16384);
                br0 = src[t]; br1 = src[256 + t]; br2 = src[512 + t]; br3 = src[768 + t];
            }
            *(int4*)&As[(rowA0 << 7) + ((chA ^ (rowA0 & 7)) << 4)] = a0;
            *(int4*)&As[(rowA1 << 7) + ((chA ^ (rowA1 & 7)) << 4)] = a1;
        }
        __syncthreads();                        // RAW: tile visible
        i32x4 af[4], bf0[4], bf1[4];
        #pragma unroll
        for (int kk = 0; kk < 4; ++kk) {
            int ch2 = kk * 2 + hi, row = wm + r;
            af[kk]  = *(const i32x4*)&As[(row << 7) + ((ch2 ^ (row & 7)) << 4)];
            bf0[kk] = *(const i32x4*)&Bs[ch2 * 2048 + ((wn + r) << 4)];
            bf1[kk] = *(const i32x4*)&Bs[ch2 * 2048 + ((wn + 32 + r) << 4)];
        }
        #pragma unroll
        for (int kk = 0; kk < 4; ++kk) {
            acc0 = __builtin_amdgcn_mfma_i32_32x32x32_i8(af[kk], bf0[kk], acc0, 0, 0, 0);
            acc1 = __builtin_amdgcn_mfma_i32_32x32x32_i8(af[kk], bf1[kk], acc1, 0, 0, 0);
        }
    }

    // corrections in-register + block min/max partials
    int o0 = wn + r, o1 = wn + 32 + r;
    int zw0 = zpw[o0], c0 = ct[o0];
    int zw1 = zpw[o1], c1 = ct[o1];
    int lmin = INT32_MAX, lmax = INT32_MIN;
    int* resp = (int*)(ws + OFF_RES);
    #pragma unroll
    for (int g = 0; g < 16; ++g) {
        int row = wm + (g & 3) + ((g >> 2) << 3) + (hi << 2);
        int s = sq[row];
        int v0 = acc0[g] + zw0 * s + c0;
        int v1 = acc1[g] + zw1 * s + c1;
        acc0[g] = v0; acc1[g] = v1;
        lmin = min(lmin, min(v0, v1));
        lmax = max(lmax, max(v0, v1));
        if (WRITE_RES) {
            int m = mg + row;
            resp[m * CO_ + o0] = v0;
            resp[m * CO_ + o1] = v1;
        }
    }
    block_iminmax(lmin, lmax, ired);
    if (t == 0) {
        ((int*)(ws + OFF_PRMIN))[blockIdx.x] = lmin;
        ((int*)(ws + OFF_PRMAX))[blockIdx.x] = lmax;
    }
    __syncthreads();
}

// ---- P4: requant + dequant from registers, LDS transpose, store out ----
__device__ __forceinline__ void dev_p4(const char* ws, char* pool, float* __restrict__ out,
                                       int abit, float sx, int rmin, int rmax,
                                       const i32x16& acc0, const i32x16& acc1) {
    const float* scale_w = (const float*)(ws + OFF_SW);
    float* tile = (float*)pool;                 // [64][129]
    int t = threadIdx.x;
    int mg = blockIdx.x * 64;
    int b = mg / L_, l0 = mg - b * L_;
    int lane = t & 63, w = t >> 6;
    int wm = (w >> 1) << 5, wn = (w & 1) << 6;
    int r = lane & 31, hi = lane >> 5;
    int o0 = wn + r, o1 = wn + 32 + r;
    int nx = 1 << (abit - 1);
    float nlev = (float)((1 << abit) - 1);
    float rminf = (float)rmin, rmaxf = (float)rmax;
    float sr = nlev / fmaxf(rmaxf - rminf, 1e-8f);
    float zr = rintf(sr * rminf) + (float)nx;
    float lo = -(float)nx, hiq = (float)(nx - 1);
    float swsx0 = scale_w[o0] * sx, swsx1 = scale_w[o1] * sx;
    #pragma unroll
    for (int g = 0; g < 16; ++g) {
        int row = wm + (g & 3) + ((g >> 2) << 3) + (hi << 2);
        float qa = fminf(fmaxf(rintf(sr * (float)acc0[g] - zr), lo), hiq);
        float qb = fminf(fmaxf(rintf(sr * (float)acc1[g] - zr), lo), hiq);
        tile[row * 129 + o0] = ((qa + zr) / sr) / swsx0;
        tile[row * 129 + o1] = ((qb + zr) / sr) / swsx1;
    }
    __syncthreads();
    #pragma unroll
    for (int i = 0; i < 8; ++i) {
        int o = (t >> 4) + i * 16;
        int l4 = (t & 15) * 4;
        float4 f;
        #pragma unroll
        for (int jj = 0; jj < 4; ++jj)
            ((float*)&f)[jj] = tile[(l4 + jj) * 129 + o];
        *(float4*)(out + ((size_t)(b * CO_ + o)) * L_ + l0 + l4) = f;
    }
}

// =================== fused cooperative kernel ===================
__global__ __launch_bounds__(256, 4) void k_fused(const float* __restrict__ x,
                                                  const float* __restrict__ wgt,
                                                  const float* __restrict__ bias,
                                                  const int* __restrict__ abit_p,
                                                  char* __restrict__ ws,
                                                  float* __restrict__ out) {
    __shared__ __align__(16) char pool[33280];
    __shared__ float sred[8];
    __shared__ int ired[8];

    int n4 = (B_ * C_ * L_) / 4;
    dev_p1((const float4*)x, n4, ws, sred);
    cg::this_grid().sync();

    float xmin, xmax;
    dev_reduce_pb(ws, sred, xmin, xmax);
    int abit = read_abit(abit_p);
    float nlv = (float)((1 << abit) - 1);
    float sx = nlv / fmaxf(xmax - xmin, 1e-8f);
    float zx = rintf(sx * xmin) + (float)(1 << (abit - 1));
    int nx = 1 << (abit - 1);
    dev_p2x(x, ws, pool, sx, zx, nx);
    if (blockIdx.x < CO_) dev_p2w(wgt, bias, ws, sred, ired, sx, zx);
    cg::this_grid().sync();

    i32x16 acc0, acc1;
    dev_p3<false>(ws, pool, ired, abit, sx, zx, acc0, acc1);
    cg::this_grid().sync();

    int rmin, rmax;
    dev_reduce_pr(ws, ired, rmin, rmax);
    dev_p4(ws, pool, out, abit, sx, rmin, rmax, acc0, acc1);
}

// =================== fallback (non-cooperative) path ===================
__global__ __launch_bounds__(256) void fb_p1(const float4* __restrict__ x4, int n4,
                                             char* __restrict__ ws) {
    __shared__ float sred[8];
    dev_p1(x4, n4, ws, sred);
}

__global__ __launch_bounds__(256) void fb_p2(const float* __restrict__ x,
                                             const float* __restrict__ wgt,
                                             const float* __restrict__ bias,
                                             const int* __restrict__ abit_p,
                                             char* __restrict__ ws) {
    __shared__ __align__(16) char pool[1024];
    __shared__ float sred[8];
    __shared__ int ired[8];
    float xmin, xmax;
    dev_reduce_pb(ws, sred, xmin, xmax);
    int abit = read_abit(abit_p);
    float nlv = (float)((1 << abit) - 1);
    float sx = nlv / fmaxf(xmax - xmin, 1e-8f);
    float zx = rintf(sx * xmin) + (float)(1 << (abit - 1));
    int nx = 1 << (abit - 1);
    dev_p2x(x, ws, pool, sx, zx, nx);
    if (blockIdx.x < CO_) dev_p2w(wgt, bias, ws, sred, ired, sx, zx);
}

__global__ __launch_bounds__(256, 4) void fb_p3(const int* __restrict__ abit_p,
                                                char* __restrict__ ws) {
    __shared__ __align__(16) char pool[25760];
    __shared__ float sred[8];
    __shared__ int ired[8];
    float xmin, xmax;
    dev_reduce_pb(ws, sred, xmin, xmax);
    int abit = read_abit(abit_p);
    float nlv = (float)((1 << abit) - 1);
    float sx = nlv / fmaxf(xmax - xmin, 1e-8f);
    float zx = rintf(sx * xmin) + (float)(1 << (abit - 1));
    i32x16 acc0, acc1;
    dev_p3<true>(ws, pool, ired, abit, sx, zx, acc0, acc1);
}

__global__ __launch_bounds__(256) void fb_p4(const int* __restrict__ abit_p,
                                             char* __restrict__ ws,
                                             float* __restrict__ out) {
    __shared__ int tile[64 * 65];
    __shared__ float sred[8];
    __shared__ int ired[8];
    float xmin, xmax;
    dev_reduce_pb(ws, sred, xmin, xmax);
    int abit = read_abit(abit_p);
    float nlv = (float)((1 << abit) - 1);
    float sxv = nlv / fmaxf(xmax - xmin, 1e-8f);
    int rmin, rmax;
    dev_reduce_pr(ws, ired, rmin, rmax);

    const int* res = (const int*)(ws + OFF_RES);
    const float* scale_w = (const float*)(ws + OFF_SW);
    int t = threadIdx.x;
    int bid = blockIdx.x;
    int lcq = bid % 49; int tmp2 = bid / 49; int ocq = tmp2 & 1; int b = tmp2 >> 1;
    int l0 = lcq * 64, o0 = ocq * 64;

    const int* resb = res + ((size_t)(b * L_ + l0)) * CO_ + o0;
    #pragma unroll
    for (int i = 0; i < 4; ++i) {
        int lr = (t >> 4) + i * 16;
        int oc4 = (t & 15) * 4;
        int4 v = *(const int4*)(resb + lr * CO_ + oc4);
        int* d = &tile[lr * 65 + oc4];
        d[0] = v.x; d[1] = v.y; d[2] = v.z; d[3] = v.w;
    }
    int nxq = 1 << (abit - 1);
    float rminf = (float)rmin, rmaxf = (float)rmax;
    float sr = nlv / fmaxf(rmaxf - rminf, 1e-8f);
    float zr = rintf(sr * rminf) + (float)nxq;
    float lo = -(float)nxq, hiq = (float)(nxq - 1);
    __syncthreads();
    #pragma unroll
    for (int i = 0; i < 4; ++i) {
        int o = (t >> 4) + i * 16;
        int l4 = (t & 15) * 4;
        float swsx = scale_w[o0 + o] * sxv;
        float4 f;
        #pragma unroll
        for (int jj = 0; jj < 4; ++jj) {
            int rv = tile[(l4 + jj) * 65 + o];
            float q = fminf(fmaxf(rintf(sr * (float)rv - zr), lo), hiq);
            ((float*)&f)[jj] = ((q + zr) / sr) / swsx;
        }
        *(float4*)(out + ((size_t)(b * CO_ + o0 + o)) * L_ + l0 + l4) = f;
    }
}

// ---------------- launch ----------------

extern "C" void kernel_launch(void* const* d_in, const int* in_sizes, int n_in,
                              void* d_out, int out_size, void* d_ws, size_t ws_size,
                              hipStream_t stream) {
    const float* x      = (const float*)d_in[0];
    const float* weight = (const float*)d_in[1];
    const float* bias   = (const float*)d_in[2];
    const int*   abit   = (const int*)d_in[3];
    float* out = (float*)d_out;
    char* ws = (char*)d_ws;

    int dev = 0;
    hipGetDevice(&dev);
    int ncu = 0;
    hipDeviceGetAttribute(&ncu, hipDeviceAttributeMultiprocessorCount, dev);
    int nb = 0;
    hipOccupancyMaxActiveBlocksPerMultiprocessor(&nb, (const void*)k_fused, 256, 0);

    if (nb > 0 && (long)nb * (long)ncu >= NT_) {
        void* args[] = {(void*)&x, (void*)&weight, (void*)&bias,
                        (void*)&abit, (void*)&ws, (void*)&out};
        hipLaunchCooperativeKernel((const void*)k_fused, dim3(NT_), dim3(256),
                                   args, 0, stream);
    } else {
        int n4 = (B_ * C_ * L_) / 4;
        fb_p1<<<NT_, 256, 0, stream>>>((const float4*)x, n4, ws);
        fb_p2<<<NT_, 256, 0, stream>>>(x, weight, bias, abit, ws);
        fb_p3<<<NT_, 256, 0, stream>>>(abit, ws);
        fb_p4<<<1568, 256, 0, stream>>>(abit, ws, out);
    }
}

// Round 10
// 57.907 us; speedup vs baseline: 2.1046x; 1.0261x over previous
//
#include <hip/hip_runtime.h>
#include <hip/hip_cooperative_groups.h>
#include <stdint.h>

#pragma clang fp contract(off)

namespace cg = cooperative_groups;

typedef __attribute__((ext_vector_type(4))) int i32x4;
typedef __attribute__((ext_vector_type(16))) int i32x16;

#define B_    16
#define C_    128
#define HW_   56
#define L_    3136
#define CO_   128
#define F_    1152
#define M_    50176
#define NT_   784          // GEMM tiles == grid blocks (8 XCD * 98)

// ---- workspace layout (bytes) ----
#define OFF_PBMIN 0        // float[784] per-block x-min partials
#define OFF_PBMAX 3136     // float[784]
#define OFF_PRMIN 6272     // int[784] per-block res-min partials
#define OFF_PRMAX 9408     // int[784]
#define OFF_SW    12544    // float scale_w[128]
#define OFF_ZPW   13056    // int zp_w[128]
#define OFF_CT    13568    // int const_term[128]
#define OFF_QW    16384    // int8 qw2[j][ch][o][16] = 147456
#define OFF_QX    163840   // int8 qx_t[b][l][c] = 6422528
#define OFF_S     6586368  // int S[b][3136] = 200704
#define OFF_RES   6787072  // int res[50176][128] (FALLBACK PATH ONLY)

__device__ __forceinline__ int read_abit(const int* p) {
    int i = *p;
    if (i > 0 && i < 32) return i;
    float f = __int_as_float(i);
    int fi = (int)f;
    return (fi > 0 && fi < 32) ? fi : 8;
}

// XCD-aware tile swizzle: consecutive tiles of one image stay on one XCD's L2
__device__ __forceinline__ int swz_tile(int blk) {
    return (blk & 7) * 98 + (blk >> 3);    // bijective on [0,784)
}

// ---- block-wide reductions (256 threads), trailing sync for LDS reuse ----
__device__ __forceinline__ void block_fminmax(float& mn, float& mx, float* sred) {
    for (int m = 32; m; m >>= 1) {
        mn = fminf(mn, __shfl_xor(mn, m));
        mx = fmaxf(mx, __shfl_xor(mx, m));
    }
    int w = threadIdx.x >> 6;
    if ((threadIdx.x & 63) == 0) { sred[w] = mn; sred[4 + w] = mx; }
    __syncthreads();
    mn = fminf(fminf(sred[0], sred[1]), fminf(sred[2], sred[3]));
    mx = fmaxf(fmaxf(sred[4], sred[5]), fmaxf(sred[6], sred[7]));
    __syncthreads();
}
__device__ __forceinline__ void block_iminmax(int& mn, int& mx, int* ired) {
    for (int m = 32; m; m >>= 1) {
        mn = min(mn, __shfl_xor(mn, m));
        mx = max(mx, __shfl_xor(mx, m));
    }
    int w = threadIdx.x >> 6;
    if ((threadIdx.x & 63) == 0) { ired[w] = mn; ired[4 + w] = mx; }
    __syncthreads();
    mn = min(min(ired[0], ired[1]), min(ired[2], ired[3]));
    mx = max(max(ired[4], ired[5]), max(ired[6], ired[7]));
    __syncthreads();
}
__device__ __forceinline__ int block_isum(int v, int* ired) {
    for (int m = 32; m; m >>= 1) v += __shfl_xor(v, m);
    int w = threadIdx.x >> 6;
    if ((threadIdx.x & 63) == 0) ired[w] = v;
    __syncthreads();
    v = ired[0] + ired[1] + ired[2] + ired[3];
    __syncthreads();
    return v;
}

// ---- P1: per-block x min/max partials (pad zeros included via 0-init) ----
__device__ __forceinline__ void dev_p1(const float4* __restrict__ x4, int n4,
                                       char* ws, float* sred) {
    float mn = 0.0f, mx = 0.0f;
    int stride = gridDim.x * blockDim.x;
    for (int i = blockIdx.x * blockDim.x + threadIdx.x; i < n4; i += stride) {
        float4 v = x4[i];
        mn = fminf(mn, fminf(fminf(v.x, v.y), fminf(v.z, v.w)));
        mx = fmaxf(mx, fmaxf(fmaxf(v.x, v.y), fmaxf(v.z, v.w)));
    }
    block_fminmax(mn, mx, sred);
    if (threadIdx.x == 0) {
        ((float*)(ws + OFF_PBMIN))[blockIdx.x] = mn;
        ((float*)(ws + OFF_PBMAX))[blockIdx.x] = mx;
    }
}

__device__ __forceinline__ void dev_reduce_pb(const char* ws, float* sred,
                                              float& xmin, float& xmax) {
    const float* pbmin = (const float*)(ws + OFF_PBMIN);
    const float* pbmax = (const float*)(ws + OFF_PBMAX);
    float mn = 0.0f, mx = 0.0f;
    for (int i = threadIdx.x; i < NT_; i += 256) {
        mn = fminf(mn, pbmin[i]);
        mx = fmaxf(mx, pbmax[i]);
    }
    block_fminmax(mn, mx, sred);
    xmin = mn; xmax = mx;
}

__device__ __forceinline__ void dev_reduce_pr(const char* ws, int* ired,
                                              int& rmin, int& rmax) {
    const int* prmin = (const int*)(ws + OFF_PRMIN);
    const int* prmax = (const int*)(ws + OFF_PRMAX);
    int mn = INT32_MAX, mx = INT32_MIN;
    for (int i = threadIdx.x; i < NT_; i += 256) {
        mn = min(mn, prmin[i]);
        mx = max(mx, prmax[i]);
    }
    block_iminmax(mn, mx, ired);
    rmin = mn; rmax = mx;
}

// ---- P2x: quantize x to channel-last qx_t + per-pixel channel sums S ----
__device__ __forceinline__ void dev_p2x(const float* __restrict__ x, char* ws, char* pool,
                                        float sx, float zx, int nx) {
    int (*ssum)[64] = (int(*)[64])pool;
    float lo = -(float)nx, hif = (float)(nx - 1);
    signed char* qxt = (signed char*)(ws + OFF_QX);
    int gid = swz_tile(blockIdx.x);
    int b = gid / 49, lcq = gid - b * 49;
    int l0 = lcq * 64;
    int t = threadIdx.x, lane = t & 63, cgp = t >> 6;
    int l = l0 + lane;
    const float* xb = x + ((size_t)b * C_) * L_ + l;
    int4* dst = (int4*)(qxt + ((size_t)(b * L_ + l)) * 128);
    int psum = 0;
    #pragma unroll
    for (int ii = 0; ii < 2; ++ii) {
        int c16 = (cgp + 4 * ii) * 16;
        int wds[4];
        #pragma unroll
        for (int k = 0; k < 4; ++k) {
            int wv = 0;
            #pragma unroll
            for (int e = 0; e < 4; ++e) {
                int c = c16 + 4 * k + e;
                float v = xb[(size_t)c * L_];
                int qi = (int)fminf(fmaxf(rintf(sx * v - zx), lo), hif);
                psum += qi;
                wv |= (qi & 255) << (8 * e);
            }
            wds[k] = wv;
        }
        int4 vv; vv.x = wds[0]; vv.y = wds[1]; vv.z = wds[2]; vv.w = wds[3];
        dst[c16 >> 4] = vv;
    }
    ssum[cgp][lane] = psum;
    __syncthreads();
    if (cgp == 0) {
        int* S = (int*)(ws + OFF_S);
        S[b * L_ + l] = ssum[0][lane] + ssum[1][lane] + ssum[2][lane] + ssum[3][lane];
    }
    __syncthreads();
}

// ---- P2w: quantize weight row o=blockIdx.x (256 threads), pack qw2[j][ch][o][16] ----
__device__ __forceinline__ void dev_p2w(const float* __restrict__ wgt,
                                        const float* __restrict__ bias,
                                        char* ws, float* sred, int* ired,
                                        float sx, float zx) {
    int o = blockIdx.x;
    const float* wr = wgt + o * F_;
    float mn = 3.4e38f, mx = -3.4e38f;
    for (int f = threadIdx.x; f < F_; f += 256) {
        float v = wr[f];
        mn = fminf(mn, v); mx = fmaxf(mx, v);
    }
    block_fminmax(mn, mx, sred);
    float sw = 255.0f / fmaxf(mx - mn, 1e-8f);
    float zw = rintf(sw * mn) + 128.0f;
    signed char* qw = (signed char*)(ws + OFF_QW);
    int qsum = 0;
    for (int f = threadIdx.x; f < F_; f += 256) {
        float q = fminf(fmaxf(rintf(sw * wr[f] - zw), -128.0f), 127.0f);
        int qi = (int)q;
        qsum += qi;
        int c = f / 9, j = f - c * 9;
        qw[j * 16384 + (c >> 4) * 2048 + (o << 4) + (c & 15)] = (signed char)qi;
    }
    qsum = block_isum(qsum, ired);
    if (threadIdx.x == 0) {
        float qb = rintf(sw * sx * bias[o]);
        int zwi = (int)zw, zxi = (int)zx;
        ((int*)(ws + OFF_CT))[o] = zxi * qsum + F_ * zwi * zxi + (int)qb;
        ((int*)(ws + OFF_ZPW))[o] = zwi;
        ((float*)(ws + OFF_SW))[o] = sw;
    }
}

// ---- P3: 64Mx128N MFMA int8 GEMM tile; corrected accs stay in registers.
// Both A and B global loads for tap j+1 issued during tap j's MFMA phase;
// barrier-to-barrier staging window is pure LDS writes.
// pool layout: As 0..8191 | Bs 8192..24575 | S_s 24576..25503 | sq 25504..25759
template <bool WRITE_RES>
__device__ __forceinline__ void dev_p3(char* __restrict__ ws, char* pool, int* ired,
                                       int abit, float sx, float zx,
                                       i32x16& acc0, i32x16& acc1) {
    signed char* As = (signed char*)pool;
    signed char* Bs = (signed char*)(pool + 8192);
    int* S_s = (int*)(pool + 24576);
    int* sq  = (int*)(pool + 25504);
    const signed char* qxt = (const signed char*)(ws + OFF_QX);
    const signed char* qw  = (const signed char*)(ws + OFF_QW);
    const int* Sg  = (const int*)(ws + OFF_S);
    const int* zpw = (const int*)(ws + OFF_ZPW);
    const int* ct  = (const int*)(ws + OFF_CT);

    int t = threadIdx.x;
    int mg = swz_tile(blockIdx.x) * 64;
    int b = mg / L_, l0 = mg - b * L_;
    int prow0 = l0 / HW_;
    int nx = 1 << (abit - 1);
    int q0 = min(max(-(int)zx, -nx), nx - 1);
    int pw = (q0 & 255) * 0x01010101;
    int4 pad4; pad4.x = pw; pad4.y = pw; pad4.z = pw; pad4.w = pw;
    int padS = C_ * q0;
    const signed char* qxtb = qxt + (size_t)b * L_ * 128;
    const int* Sb = Sg + b * L_;

    int chA = t & 7, rowA0 = t >> 3, rowA1 = rowA0 + 32;
    int li0 = l0 + rowA0, li1 = l0 + rowA1;
    int oh0 = li0 / HW_, ow0 = li0 - oh0 * HW_;
    int oh1 = li1 / HW_, ow1 = li1 - oh1 * HW_;

    int4 a0, a1, br0, br1, br2, br3;
    #define P3_LOAD_A(J) do {                                                          \
        int kh = (J) / 3 - 1, kw = (J) % 3 - 1;                                        \
        int ih = oh0 + kh, iw = ow0 + kw;                                              \
        a0 = ((unsigned)ih < HW_ && (unsigned)iw < HW_)                                \
             ? *(const int4*)(qxtb + ((ih * HW_ + iw) << 7) + (chA << 4)) : pad4;      \
        ih = oh1 + kh; iw = ow1 + kw;                                                  \
        a1 = ((unsigned)ih < HW_ && (unsigned)iw < HW_)                                \
             ? *(const int4*)(qxtb + ((ih * HW_ + iw) << 7) + (chA << 4)) : pad4;      \
    } while (0)
    #define P3_LOAD_B(J) do {                                                          \
        const int4* src = (const int4*)(qw + (J) * 16384);                             \
        br0 = src[t]; br1 = src[256 + t]; br2 = src[512 + t]; br3 = src[768 + t];      \
    } while (0)

    // prologue: issue tap0 loads, stage S halo
    P3_LOAD_A(0); P3_LOAD_B(0);
    if (t < 232) {
        int ri = t / 58, c1 = t - ri * 58;
        int ih = prow0 - 1 + ri, iw = c1 - 1;
        S_s[t] = ((unsigned)ih < HW_ && (unsigned)iw < HW_) ? Sb[ih * HW_ + iw] : padS;
    }
    __syncthreads();
    if (t < 64) {               // per-row 3x3 box sums
        int l = l0 + t;
        int oh = l / HW_, ow = l - oh * HW_;
        int ri = oh - prow0 + 1, ci = ow + 1;
        int s = 0;
        #pragma unroll
        for (int dr = -1; dr <= 1; ++dr)
            #pragma unroll
            for (int dc = -1; dc <= 1; ++dc)
                s += S_s[(ri + dr) * 58 + ci + dc];
        sq[t] = s;
    }

    int lane = t & 63, w = t >> 6;
    int wm = (w >> 1) << 5, wn = (w & 1) << 6;
    int r = lane & 31, hi = lane >> 5;
    #pragma unroll
    for (int i = 0; i < 16; ++i) { acc0[i] = 0; acc1[i] = 0; }

    #pragma unroll
    for (int j = 0; j < 9; ++j) {
        if (j > 0) __syncthreads();            // WAR: previous tap's reads done
        // staging window: pure LDS writes from prefetched regs
        *(int4*)&As[(rowA0 << 7) + ((chA ^ (rowA0 & 7)) << 4)] = a0;
        *(int4*)&As[(rowA1 << 7) + ((chA ^ (rowA1 & 7)) << 4)] = a1;
        {
            int4* d = (int4*)Bs;
            d[t] = br0; d[256 + t] = br1; d[512 + t] = br2; d[768 + t] = br3;
        }
        // issue next tap's loads; they complete under this tap's MFMA phase
        if (j < 8) { P3_LOAD_A(j + 1); P3_LOAD_B(j + 1); }
        __syncthreads();                        // RAW: tile visible
        i32x4 af[4], bf0[4], bf1[4];
        #pragma unroll
        for (int kk = 0; kk < 4; ++kk) {
            int ch2 = kk * 2 + hi, row = wm + r;
            af[kk]  = *(const i32x4*)&As[(row << 7) + ((ch2 ^ (row & 7)) << 4)];
            bf0[kk] = *(const i32x4*)&Bs[ch2 * 2048 + ((wn + r) << 4)];
            bf1[kk] = *(const i32x4*)&Bs[ch2 * 2048 + ((wn + 32 + r) << 4)];
        }
        #pragma unroll
        for (int kk = 0; kk < 4; ++kk) {
            acc0 = __builtin_amdgcn_mfma_i32_32x32x32_i8(af[kk], bf0[kk], acc0, 0, 0, 0);
            acc1 = __builtin_amdgcn_mfma_i32_32x32x32_i8(af[kk], bf1[kk], acc1, 0, 0, 0);
        }
    }
    #undef P3_LOAD_A
    #undef P3_LOAD_B

    // corrections in-register + block min/max partials
    int o0 = wn + r, o1 = wn + 32 + r;
    int zw0 = zpw[o0], c0 = ct[o0];
    int zw1 = zpw[o1], c1 = ct[o1];
    int lmin = INT32_MAX, lmax = INT32_MIN;
    int* resp = (int*)(ws + OFF_RES);
    #pragma unroll
    for (int g = 0; g < 16; ++g) {
        int row = wm + (g & 3) + ((g >> 2) << 3) + (hi << 2);
        int s = sq[row];
        int v0 = acc0[g] + zw0 * s + c0;
        int v1 = acc1[g] + zw1 * s + c1;
        acc0[g] = v0; acc1[g] = v1;
        lmin = min(lmin, min(v0, v1));
        lmax = max(lmax, max(v0, v1));
        if (WRITE_RES) {
            int m = mg + row;
            resp[m * CO_ + o0] = v0;
            resp[m * CO_ + o1] = v1;
        }
    }
    block_iminmax(lmin, lmax, ired);
    if (t == 0) {
        ((int*)(ws + OFF_PRMIN))[blockIdx.x] = lmin;
        ((int*)(ws + OFF_PRMAX))[blockIdx.x] = lmax;
    }
    __syncthreads();
}

// ---- P4: requant + dequant from registers, LDS transpose, store out ----
__device__ __forceinline__ void dev_p4(const char* ws, char* pool, float* __restrict__ out,
                                       int abit, float sx, int rmin, int rmax,
                                       const i32x16& acc0, const i32x16& acc1) {
    const float* scale_w = (const float*)(ws + OFF_SW);
    float* tile = (float*)pool;                 // [64][129]
    int t = threadIdx.x;
    int mg = swz_tile(blockIdx.x) * 64;
    int b = mg / L_, l0 = mg - b * L_;
    int lane = t & 63, w = t >> 6;
    int wm = (w >> 1) << 5, wn = (w & 1) << 6;
    int r = lane & 31, hi = lane >> 5;
    int o0 = wn + r, o1 = wn + 32 + r;
    int nx = 1 << (abit - 1);
    float nlev = (float)((1 << abit) - 1);
    float rminf = (float)rmin, rmaxf = (float)rmax;
    float sr = nlev / fmaxf(rmaxf - rminf, 1e-8f);
    float zr = rintf(sr * rminf) + (float)nx;
    float lo = -(float)nx, hiq = (float)(nx - 1);
    float swsx0 = scale_w[o0] * sx, swsx1 = scale_w[o1] * sx;
    #pragma unroll
    for (int g = 0; g < 16; ++g) {
        int row = wm + (g & 3) + ((g >> 2) << 3) + (hi << 2);
        float qa = fminf(fmaxf(rintf(sr * (float)acc0[g] - zr), lo), hiq);
        float qb = fminf(fmaxf(rintf(sr * (float)acc1[g] - zr), lo), hiq);
        tile[row * 129 + o0] = ((qa + zr) / sr) / swsx0;
        tile[row * 129 + o1] = ((qb + zr) / sr) / swsx1;
    }
    __syncthreads();
    #pragma unroll
    for (int i = 0; i < 8; ++i) {
        int o = (t >> 4) + i * 16;
        int l4 = (t & 15) * 4;
        float4 f;
        #pragma unroll
        for (int jj = 0; jj < 4; ++jj)
            ((float*)&f)[jj] = tile[(l4 + jj) * 129 + o];
        *(float4*)(out + ((size_t)(b * CO_ + o)) * L_ + l0 + l4) = f;
    }
}

// =================== fused cooperative kernel ===================
__global__ __launch_bounds__(256, 4) void k_fused(const float* __restrict__ x,
                                                  const float* __restrict__ wgt,
                                                  const float* __restrict__ bias,
                                                  const int* __restrict__ abit_p,
                                                  char* __restrict__ ws,
                                                  float* __restrict__ out) {
    __shared__ __align__(16) char pool[33280];
    __shared__ float sred[8];
    __shared__ int ired[8];

    int n4 = (B_ * C_ * L_) / 4;
    dev_p1((const float4*)x, n4, ws, sred);
    cg::this_grid().sync();

    float xmin, xmax;
    dev_reduce_pb(ws, sred, xmin, xmax);
    int abit = read_abit(abit_p);
    float nlv = (float)((1 << abit) - 1);
    float sx = nlv / fmaxf(xmax - xmin, 1e-8f);
    float zx = rintf(sx * xmin) + (float)(1 << (abit - 1));
    int nx = 1 << (abit - 1);
    dev_p2x(x, ws, pool, sx, zx, nx);
    if (blockIdx.x < CO_) dev_p2w(wgt, bias, ws, sred, ired, sx, zx);
    cg::this_grid().sync();

    i32x16 acc0, acc1;
    dev_p3<false>(ws, pool, ired, abit, sx, zx, acc0, acc1);
    cg::this_grid().sync();

    int rmin, rmax;
    dev_reduce_pr(ws, ired, rmin, rmax);
    dev_p4(ws, pool, out, abit, sx, rmin, rmax, acc0, acc1);
}

// =================== fallback (non-cooperative) path ===================
__global__ __launch_bounds__(256) void fb_p1(const float4* __restrict__ x4, int n4,
                                             char* __restrict__ ws) {
    __shared__ float sred[8];
    dev_p1(x4, n4, ws, sred);
}

__global__ __launch_bounds__(256) void fb_p2(const float* __restrict__ x,
                                             const float* __restrict__ wgt,
                                             const float* __restrict__ bias,
                                             const int* __restrict__ abit_p,
                                             char* __restrict__ ws) {
    __shared__ __align__(16) char pool[1024];
    __shared__ float sred[8];
    __shared__ int ired[8];
    float xmin, xmax;
    dev_reduce_pb(ws, sred, xmin, xmax);
    int abit = read_abit(abit_p);
    float nlv = (float)((1 << abit) - 1);
    float sx = nlv / fmaxf(xmax - xmin, 1e-8f);
    float zx = rintf(sx * xmin) + (float)(1 << (abit - 1));
    int nx = 1 << (abit - 1);
    dev_p2x(x, ws, pool, sx, zx, nx);
    if (blockIdx.x < CO_) dev_p2w(wgt, bias, ws, sred, ired, sx, zx);
}

__global__ __launch_bounds__(256, 4) void fb_p3(const int* __restrict__ abit_p,
                                                char* __restrict__ ws) {
    __shared__ __align__(16) char pool[25760];
    __shared__ float sred[8];
    __shared__ int ired[8];
    float xmin, xmax;
    dev_reduce_pb(ws, sred, xmin, xmax);
    int abit = read_abit(abit_p);
    float nlv = (float)((1 << abit) - 1);
    float sx = nlv / fmaxf(xmax - xmin, 1e-8f);
    float zx = rintf(sx * xmin) + (float)(1 << (abit - 1));
    i32x16 acc0, acc1;
    dev_p3<true>(ws, pool, ired, abit, sx, zx, acc0, acc1);
}

__global__ __launch_bounds__(256) void fb_p4(const int* __restrict__ abit_p,
                                             char* __restrict__ ws,
                                             float* __restrict__ out) {
    __shared__ int tile[64 * 65];
    __shared__ float sred[8];
    __shared__ int ired[8];
    float xmin, xmax;
    dev_reduce_pb(ws, sred, xmin, xmax);
    int abit = read_abit(abit_p);
    float nlv = (float)((1 << abit) - 1);
    float sxv = nlv / fmaxf(xmax - xmin, 1e-8f);
    int rmin, rmax;
    dev_reduce_pr(ws, ired, rmin, rmax);

    const int* res = (const int*)(ws + OFF_RES);
    const float* scale_w = (const float*)(ws + OFF_SW);
    int t = threadIdx.x;
    int bid = blockIdx.x;
    int lcq = bid % 49; int tmp2 = bid / 49; int ocq = tmp2 & 1; int b = tmp2 >> 1;
    int l0 = lcq * 64, o0 = ocq * 64;

    const int* resb = res + ((size_t)(b * L_ + l0)) * CO_ + o0;
    #pragma unroll
    for (int i = 0; i < 4; ++i) {
        int lr = (t >> 4) + i * 16;
        int oc4 = (t & 15) * 4;
        int4 v = *(const int4*)(resb + lr * CO_ + oc4);
        int* d = &tile[lr * 65 + oc4];
        d[0] = v.x; d[1] = v.y; d[2] = v.z; d[3] = v.w;
    }
    int nxq = 1 << (abit - 1);
    float rminf = (float)rmin, rmaxf = (float)rmax;
    float sr = nlv / fmaxf(rmaxf - rminf, 1e-8f);
    float zr = rintf(sr * rminf) + (float)nxq;
    float lo = -(float)nxq, hiq = (float)(nxq - 1);
    __syncthreads();
    #pragma unroll
    for (int i = 0; i < 4; ++i) {
        int o = (t >> 4) + i * 16;
        int l4 = (t & 15) * 4;
        float swsx = scale_w[o0 + o] * sxv;
        float4 f;
        #pragma unroll
        for (int jj = 0; jj < 4; ++jj) {
            int rv = tile[(l4 + jj) * 65 + o];
            float q = fminf(fmaxf(rintf(sr * (float)rv - zr), lo), hiq);
            ((float*)&f)[jj] = ((q + zr) / sr) / swsx;
        }
        *(float4*)(out + ((size_t)(b * CO_ + o0 + o)) * L_ + l0 + l4) = f;
    }
}

// ---------------- launch ----------------

extern "C" void kernel_launch(void* const* d_in, const int* in_sizes, int n_in,
                              void* d_out, int out_size, void* d_ws, size_t ws_size,
                              hipStream_t stream) {
    const float* x      = (const float*)d_in[0];
    const float* weight = (const float*)d_in[1];
    const float* bias   = (const float*)d_in[2];
    const int*   abit   = (const int*)d_in[3];
    float* out = (float*)d_out;
    char* ws = (char*)d_ws;

    int dev = 0;
    hipGetDevice(&dev);
    int ncu = 0;
    hipDeviceGetAttribute(&ncu, hipDeviceAttributeMultiprocessorCount, dev);
    int nb = 0;
    hipOccupancyMaxActiveBlocksPerMultiprocessor(&nb, (const void*)k_fused, 256, 0);

    if (nb > 0 && (long)nb * (long)ncu >= NT_) {
        void* args[] = {(void*)&x, (void*)&weight, (void*)&bias,
                        (void*)&abit, (void*)&ws, (void*)&out};
        hipLaunchCooperativeKernel((const void*)k_fused, dim3(NT_), dim3(256),
                                   args, 0, stream);
    } else {
        int n4 = (B_ * C_ * L_) / 4;
        fb_p1<<<NT_, 256, 0, stream>>>((const float4*)x, n4, ws);
        fb_p2<<<NT_, 256, 0, stream>>>(x, weight, bias, abit, ws);
        fb_p3<<<NT_, 256, 0, stream>>>(abit, ws);
        fb_p4<<<1568, 256, 0, stream>>>(abit, ws, out);
    }
}